// Round 4
// baseline (21163.197 us; speedup 1.0000x reference)
//
#include <hip/hip_runtime.h>
#include <math.h>

#define H 128
#define TB 16
#define XSTR 20          // padded LDS row stride (floats); 80B => float4 always 16B-aligned
#define TENC 20
#define TDEC 25

// ws layout (float offsets) — all weight blocks are [K][512] with the 512
// permuted as [kg(64)][q(8)], q = gate(2b)<<1 | half: values for hidden pair
// (2*kg, 2*kg+1) of gates i,f (first float4) and g,o (second float4).
#define OFF_E0IH 0
#define OFF_E0HH (OFF_E0IH + 7*512)        // 3584
#define OFF_E1IH (OFF_E0HH + 128*512)      // 69120
#define OFF_E1HH (OFF_E1IH + 128*512)      // 134656
#define OFF_D0IH (OFF_E1HH + 128*512)      // 200192
#define OFF_D0HH (OFF_D0IH + 2*512)        // 201216
#define OFF_D1IH (OFF_D0HH + 128*512)      // 266752
#define OFF_D1HH (OFF_D1IH + 128*512)      // 332288
#define OFF_BE0  (OFF_D1HH + 128*512)      // 397824
#define OFF_BE1  (OFF_BE0 + 512)
#define OFF_BD0  (OFF_BE1 + 512)
#define OFF_BD1  (OFF_BD0 + 512)
#define WS_FLOATS (OFF_BD1 + 512)          // 399872 floats = 1.6 MB

__global__ void prep_kernel(
    const float* __restrict__ e0ih, const float* __restrict__ e0hh,
    const float* __restrict__ e1ih, const float* __restrict__ e1hh,
    const float* __restrict__ d0ih, const float* __restrict__ d0hh,
    const float* __restrict__ d1ih, const float* __restrict__ d1hh,
    const float* __restrict__ be0i, const float* __restrict__ be0h,
    const float* __restrict__ be1i, const float* __restrict__ be1h,
    const float* __restrict__ bd0i, const float* __restrict__ bd0h,
    const float* __restrict__ bd1i, const float* __restrict__ bd1h,
    float* __restrict__ ws)
{
  int idx = blockIdx.x * blockDim.x + threadIdx.x;
  if (idx >= WS_FLOATS) return;
  const float* in; int K; int n;
  if (idx < 3584)        { in=e0ih; K=7;   n=idx-OFF_E0IH; }
  else if (idx < 69120)  { in=e0hh; K=128; n=idx-OFF_E0HH; }
  else if (idx < 134656) { in=e1ih; K=128; n=idx-OFF_E1IH; }
  else if (idx < 200192) { in=e1hh; K=128; n=idx-OFF_E1HH; }
  else if (idx < 201216) { in=d0ih; K=2;   n=idx-OFF_D0IH; }
  else if (idx < 266752) { in=d0hh; K=128; n=idx-OFF_D0HH; }
  else if (idx < 332288) { in=d1ih; K=128; n=idx-OFF_D1IH; }
  else if (idx < 397824) { in=d1hh; K=128; n=idx-OFF_D1HH; }
  else {
    int b = idx - OFF_BE0;
    int which = b >> 9, r = b & 511;
    int kg = r >> 3, q = r & 7;
    int row = (q>>1)*128 + 2*kg + (q&1);
    float v;
    if      (which==0) v = be0i[row]+be0h[row];
    else if (which==1) v = be1i[row]+be1h[row];
    else if (which==2) v = bd0i[row]+bd0h[row];
    else               v = bd1i[row]+bd1h[row];
    ws[idx] = v;
    return;
  }
  // in is (512, K) row-major, gate order i,f,g,o; write permuted k-major
  int k = n / 512, r = n - k*512;
  int kg = r >> 3, q = r & 7;
  int row = (q>>1)*128 + 2*kg + (q&1);
  ws[idx] = in[row*K + k];
}

__device__ __forceinline__ float sigm(float x) { return 1.0f/(1.0f + __expf(-x)); }
__device__ __forceinline__ float tanh_fast(float x) {
  x = fminf(fmaxf(x, -15.0f), 15.0f);
  float e = __expf(2.0f*x);
  return (e-1.0f)/(e+1.0f);
}

// acc[gate(4)][half(2)][sample(4)]; WT is [D][512] permuted; xin stride XSTR.
template<int D>
__device__ __forceinline__ void gemm1(float acc[4][2][4],
    const float* __restrict__ WT, const float* xin, int kg, int my_s)
{
  auto body = [&](int k) {
    float4 wA = *(const float4*)(WT + k*512 + kg*8);      // i0,i1,f0,f1
    float4 wB = *(const float4*)(WT + k*512 + kg*8 + 4);  // g0,g1,o0,o1
    float4 xv = *(const float4*)(xin + k*XSTR + my_s);    // aligned b128 broadcast
    float xvv[4] = {xv.x, xv.y, xv.z, xv.w};
    #pragma unroll
    for (int s=0; s<4; ++s) {
      acc[0][0][s] = fmaf(wA.x, xvv[s], acc[0][0][s]);
      acc[0][1][s] = fmaf(wA.y, xvv[s], acc[0][1][s]);
      acc[1][0][s] = fmaf(wA.z, xvv[s], acc[1][0][s]);
      acc[1][1][s] = fmaf(wA.w, xvv[s], acc[1][1][s]);
      acc[2][0][s] = fmaf(wB.x, xvv[s], acc[2][0][s]);
      acc[2][1][s] = fmaf(wB.y, xvv[s], acc[2][1][s]);
      acc[3][0][s] = fmaf(wB.z, xvv[s], acc[3][0][s]);
      acc[3][1][s] = fmaf(wB.w, xvv[s], acc[3][1][s]);
    }
  };
  if constexpr (D >= 16) {
    #pragma unroll 4
    for (int k=0; k<D; ++k) body(k);
  } else {
    #pragma unroll
    for (int k=0; k<D; ++k) body(k);
  }
}

// One LSTM layer step for this block's 16-sample tile. Single pass, all gates.
template<int D>
__device__ __forceinline__ void layer_step(
    const float* __restrict__ wtih, const float* __restrict__ wthh,
    const float* __restrict__ bias, const float* xin,
    float* hbuf, float cC[2][4], int kg, int my_s)
{
  float acc[4][2][4];
  {
    float4 bA = *(const float4*)(bias + kg*8);      // i0,i1,f0,f1
    float4 bB = *(const float4*)(bias + kg*8 + 4);  // g0,g1,o0,o1
    #pragma unroll
    for (int s=0; s<4; ++s) {
      acc[0][0][s]=bA.x; acc[0][1][s]=bA.y;
      acc[1][0][s]=bA.z; acc[1][1][s]=bA.w;
      acc[2][0][s]=bB.x; acc[2][1][s]=bB.y;
      acc[3][0][s]=bB.z; acc[3][1][s]=bB.w;
    }
  }
  gemm1<D>(acc, wtih, xin,  kg, my_s);
  gemm1<H>(acc, wthh, hbuf, kg, my_s);

  __syncthreads();   // all reads of hbuf complete before overwrite
  #pragma unroll
  for (int h=0; h<2; ++h) {
    float hv[4];
    #pragma unroll
    for (int s=0; s<4; ++s) {
      float iv = sigm(acc[0][h][s]);
      float fv = sigm(acc[1][h][s]);
      float gv = tanh_fast(acc[2][h][s]);
      float ov = sigm(acc[3][h][s]);
      float c  = fv * cC[h][s] + iv * gv;
      cC[h][s] = c;
      hv[s] = ov * tanh_fast(c);
    }
    float4 hw; hw.x=hv[0]; hw.y=hv[1]; hw.z=hv[2]; hw.w=hv[3];
    *(float4*)&hbuf[(2*kg+h)*XSTR + my_s] = hw;   // aligned b128
  }
  __syncthreads();
}

__global__ __launch_bounds__(256)
__attribute__((amdgpu_waves_per_eu(4,4)))
void lstm_main(
    const float* __restrict__ target, const float* __restrict__ ws,
    const float* __restrict__ outW, const float* __restrict__ outB,
    float* __restrict__ out)
{
  __shared__ float h0s[H*XSTR];   // 10240 B
  __shared__ float h1s[H*XSTR];   // 10240 B
  __shared__ float xs[7*XSTR];    // enc inputs; dec: rows 0-1 = x feedback
  __shared__ float ps[8*TB];      // projection partials [oh][s]

  const int tid = threadIdx.x;
  const int kg = tid & 63;        // hidden-pair index 0..63 (= lane id)
  const int sg = tid >> 6;        // sample group 0..3 (uniform per wave)
  const int my_s = sg*4;
  const long sbase = (long)blockIdx.x * TB;

  float c0[2][4], c1[2][4];
  #pragma unroll
  for (int a=0; a<2; ++a)
    #pragma unroll
    for (int b=0; b<4; ++b) { c0[a][b]=0.f; c1[a][b]=0.f; }

  for (int i=tid; i<H*XSTR; i+=256) { h0s[i]=0.f; h1s[i]=0.f; }
  __syncthreads();

  const float* WT_e0ih = ws + OFF_E0IH;
  const float* WT_e0hh = ws + OFF_E0HH;
  const float* WT_e1ih = ws + OFF_E1IH;
  const float* WT_e1hh = ws + OFF_E1HH;
  const float* WT_d0ih = ws + OFF_D0IH;
  const float* WT_d0hh = ws + OFF_D0HH;
  const float* WT_d1ih = ws + OFF_D1IH;
  const float* WT_d1hh = ws + OFF_D1HH;
  const float* B_e0 = ws + OFF_BE0;
  const float* B_e1 = ws + OFF_BE1;
  const float* B_d0 = ws + OFF_BD0;
  const float* B_d1 = ws + OFF_BD1;

  // ---------------- encoder ----------------
  for (int t=0; t<TENC; ++t) {
    if (tid < 7*TB) {
      int s = tid / 7, d = tid - s*7;
      xs[d*XSTR + s] = target[(sbase + s)*(TENC*7) + t*7 + d];
    }
    __syncthreads();
    layer_step<7>(WT_e0ih, WT_e0hh, B_e0, xs,  h0s, c0, kg, my_s);
    layer_step<H>(WT_e1ih, WT_e1hh, B_e1, h0s, h1s, c1, kg, my_s);
  }

  // ---------------- decoder ----------------
  if (tid < 2*TB) {
    int o = tid >> 4, s = tid & 15;
    xs[o*XSTR + s] = 0.f;          // x0 = zeros(B,2)
  }
  __syncthreads();
  const float ob0 = outB[0], ob1 = outB[1];

  for (int p=0; p<TDEC; ++p) {
    layer_step<2>(WT_d0ih, WT_d0hh, B_d0, xs,  h0s, c0, kg, my_s);
    layer_step<H>(WT_d1ih, WT_d1hh, B_d1, h0s, h1s, c1, kg, my_s);

    // projection: pred[s][o] = h1[:,s] . outW[o,:] + outB[o]
    if (tid < 8*TB) {
      int s = tid & 15, oh = tid >> 4;       // oh = quarter*2 + o
      int o = oh & 1, quarter = oh >> 1;
      const float* wo = outW + o*128 + quarter*32;
      const float* hc = h1s + (quarter*32)*XSTR + s;
      float acc = 0.f;
      #pragma unroll 8
      for (int k=0; k<32; ++k) acc = fmaf(hc[k*XSTR], wo[k], acc);
      ps[oh*TB + s] = acc;
    }
    __syncthreads();
    if (tid < 2*TB) {
      int o = tid >> 4, s = tid & 15;
      float pred = ps[(0*2+o)*TB + s] + ps[(1*2+o)*TB + s]
                 + ps[(2*2+o)*TB + s] + ps[(3*2+o)*TB + s]
                 + (o ? ob1 : ob0);
      out[((sbase + s)*TDEC + p)*2 + o] = pred;
      xs[o*XSTR + s] = pred;               // x for next decoder step
    }
    __syncthreads();
  }
}

extern "C" void kernel_launch(void* const* d_in, const int* in_sizes, int n_in,
                              void* d_out, int out_size, void* d_ws, size_t ws_size,
                              hipStream_t stream)
{
  const float* target = (const float*)d_in[0];
  const float* e0ih=(const float*)d_in[4],  *e0hh=(const float*)d_in[5];
  const float* be0i=(const float*)d_in[6],  *be0h=(const float*)d_in[7];
  const float* e1ih=(const float*)d_in[8],  *e1hh=(const float*)d_in[9];
  const float* be1i=(const float*)d_in[10], *be1h=(const float*)d_in[11];
  const float* d0ih=(const float*)d_in[12], *d0hh=(const float*)d_in[13];
  const float* bd0i=(const float*)d_in[14], *bd0h=(const float*)d_in[15];
  const float* d1ih=(const float*)d_in[16], *d1hh=(const float*)d_in[17];
  const float* bd1i=(const float*)d_in[18], *bd1h=(const float*)d_in[19];
  const float* outW=(const float*)d_in[20], *outB=(const float*)d_in[21];
  float* ws  = (float*)d_ws;
  float* out = (float*)d_out;
  const int B = in_sizes[0] / (TENC*7);     // 65536

  hipLaunchKernelGGL(prep_kernel, dim3((WS_FLOATS+255)/256), dim3(256), 0, stream,
      e0ih,e0hh,e1ih,e1hh,d0ih,d0hh,d1ih,d1hh,
      be0i,be0h,be1i,be1h,bd0i,bd0h,bd1i,bd1h, ws);
  hipLaunchKernelGGL(lstm_main, dim3(B/TB), dim3(256), 0, stream,
      target, ws, outW, outB, out);
}

// Round 5
// 19046.759 us; speedup vs baseline: 1.1111x; 1.1111x over previous
//
#include <hip/hip_runtime.h>
#include <math.h>

#define H 128
#define TB 16
#define XSTR 20          // padded LDS row stride (floats); 80B => float4 16B-aligned
#define TENC 20
#define TDEC 25

// ws layout (float offsets) — all weight blocks are [K][512] with the 512
// permuted as j = hh*4 + g (hh = hidden 0..127, g = gate i,f,g,o):
// W'[k][hh*4+g] = Worig[g*128+hh][k]. Each thread reads one float4 = its
// hidden's 4 gate weights.
#define OFF_E0IH 0
#define OFF_E0HH (OFF_E0IH + 7*512)        // 3584
#define OFF_E1IH (OFF_E0HH + 128*512)      // 69120
#define OFF_E1HH (OFF_E1IH + 128*512)      // 134656
#define OFF_D0IH (OFF_E1HH + 128*512)      // 200192
#define OFF_D0HH (OFF_D0IH + 2*512)        // 201216
#define OFF_D1IH (OFF_D0HH + 128*512)      // 266752
#define OFF_D1HH (OFF_D1IH + 128*512)      // 332288
#define OFF_BE0  (OFF_D1HH + 128*512)      // 397824
#define OFF_BE1  (OFF_BE0 + 512)
#define OFF_BD0  (OFF_BE1 + 512)
#define OFF_BD1  (OFF_BD0 + 512)
#define WS_FLOATS (OFF_BD1 + 512)          // 399872 floats = 1.6 MB

__global__ void prep_kernel(
    const float* __restrict__ e0ih, const float* __restrict__ e0hh,
    const float* __restrict__ e1ih, const float* __restrict__ e1hh,
    const float* __restrict__ d0ih, const float* __restrict__ d0hh,
    const float* __restrict__ d1ih, const float* __restrict__ d1hh,
    const float* __restrict__ be0i, const float* __restrict__ be0h,
    const float* __restrict__ be1i, const float* __restrict__ be1h,
    const float* __restrict__ bd0i, const float* __restrict__ bd0h,
    const float* __restrict__ bd1i, const float* __restrict__ bd1h,
    float* __restrict__ ws)
{
  int idx = blockIdx.x * blockDim.x + threadIdx.x;
  if (idx >= WS_FLOATS) return;
  const float* in; int K; int n;
  if (idx < 3584)        { in=e0ih; K=7;   n=idx-OFF_E0IH; }
  else if (idx < 69120)  { in=e0hh; K=128; n=idx-OFF_E0HH; }
  else if (idx < 134656) { in=e1ih; K=128; n=idx-OFF_E1IH; }
  else if (idx < 200192) { in=e1hh; K=128; n=idx-OFF_E1HH; }
  else if (idx < 201216) { in=d0ih; K=2;   n=idx-OFF_D0IH; }
  else if (idx < 266752) { in=d0hh; K=128; n=idx-OFF_D0HH; }
  else if (idx < 332288) { in=d1ih; K=128; n=idx-OFF_D1IH; }
  else if (idx < 397824) { in=d1hh; K=128; n=idx-OFF_D1HH; }
  else {
    int b = idx - OFF_BE0;
    int which = b >> 9, r = b & 511;
    int hh = r >> 2, g = r & 3;
    int row = g*128 + hh;
    float v;
    if      (which==0) v = be0i[row]+be0h[row];
    else if (which==1) v = be1i[row]+be1h[row];
    else if (which==2) v = bd0i[row]+bd0h[row];
    else               v = bd1i[row]+bd1h[row];
    ws[idx] = v;
    return;
  }
  // in is (512, K) row-major, gate order i,f,g,o; write permuted k-major
  int k = n / 512, r = n - k*512;
  int hh = r >> 2, g = r & 3;
  int row = g*128 + hh;
  ws[idx] = in[row*K + k];
}

__device__ __forceinline__ float sigm(float x) { return 1.0f/(1.0f + __expf(-x)); }
__device__ __forceinline__ float tanh_fast(float x) {
  x = fminf(fmaxf(x, -15.0f), 15.0f);
  float e = __expf(2.0f*x);
  return (e-1.0f)/(e+1.0f);
}

// acc[gate(4)][sample(4)]; WT is [D][512] permuted; xin stride XSTR.
template<int D>
__device__ __forceinline__ void gemm1(float acc[4][4],
    const float* __restrict__ WT, const float* xin, int hh, int my_s)
{
  auto body = [&](int k) {
    float4 w  = *(const float4*)(WT + k*512 + hh*4);    // i,f,g,o for hidden hh
    float4 xv = *(const float4*)(xin + k*XSTR + my_s);  // aligned b128 broadcast
    float xvv[4] = {xv.x, xv.y, xv.z, xv.w};
    #pragma unroll
    for (int s=0; s<4; ++s) {
      acc[0][s] = fmaf(w.x, xvv[s], acc[0][s]);
      acc[1][s] = fmaf(w.y, xvv[s], acc[1][s]);
      acc[2][s] = fmaf(w.z, xvv[s], acc[2][s]);
      acc[3][s] = fmaf(w.w, xvv[s], acc[3][s]);
    }
  };
  if constexpr (D >= 16) {
    #pragma unroll 4
    for (int k=0; k<D; ++k) body(k);
  } else {
    #pragma unroll
    for (int k=0; k<D; ++k) body(k);
  }
}

// One LSTM layer step for this block's 16-sample tile. Single pass, all gates.
template<int D>
__device__ __forceinline__ void layer_step(
    const float* __restrict__ wtih, const float* __restrict__ wthh,
    const float* __restrict__ bias, const float* xin,
    float* hbuf, float cC[4], int hh, int my_s)
{
  float acc[4][4];
  {
    float4 b = *(const float4*)(bias + hh*4);   // i,f,g,o
    #pragma unroll
    for (int s=0; s<4; ++s) {
      acc[0][s]=b.x; acc[1][s]=b.y; acc[2][s]=b.z; acc[3][s]=b.w;
    }
  }
  gemm1<D>(acc, wtih, xin,  hh, my_s);
  gemm1<H>(acc, wthh, hbuf, hh, my_s);

  __syncthreads();   // all reads of hbuf complete before overwrite
  float hv[4];
  #pragma unroll
  for (int s=0; s<4; ++s) {
    float iv = sigm(acc[0][s]);
    float fv = sigm(acc[1][s]);
    float gv = tanh_fast(acc[2][s]);
    float ov = sigm(acc[3][s]);
    float c  = fv * cC[s] + iv * gv;
    cC[s] = c;
    hv[s] = ov * tanh_fast(c);
  }
  float4 hw; hw.x=hv[0]; hw.y=hv[1]; hw.z=hv[2]; hw.w=hv[3];
  *(float4*)&hbuf[hh*XSTR + my_s] = hw;   // aligned b128
  __syncthreads();
}

__global__ __launch_bounds__(512)
void lstm_main(
    const float* __restrict__ target, const float* __restrict__ ws,
    const float* __restrict__ outW, const float* __restrict__ outB,
    float* __restrict__ out)
{
  __shared__ float h0s[H*XSTR];   // 10240 B
  __shared__ float h1s[H*XSTR];   // 10240 B
  __shared__ float xs[7*XSTR];    // enc inputs; dec: rows 0-1 = x feedback
  __shared__ float ps[8*TB];      // projection partials [oh][s]

  const int tid = threadIdx.x;
  const int hh = tid & 127;       // hidden index 0..127
  const int sg = tid >> 7;        // sample group 0..3 (wave-uniform)
  const int my_s = sg*4;
  const long sbase = (long)blockIdx.x * TB;

  float c0[4], c1[4];
  #pragma unroll
  for (int b=0; b<4; ++b) { c0[b]=0.f; c1[b]=0.f; }

  for (int i=tid; i<H*XSTR; i+=512) { h0s[i]=0.f; h1s[i]=0.f; }
  __syncthreads();

  const float* WT_e0ih = ws + OFF_E0IH;
  const float* WT_e0hh = ws + OFF_E0HH;
  const float* WT_e1ih = ws + OFF_E1IH;
  const float* WT_e1hh = ws + OFF_E1HH;
  const float* WT_d0ih = ws + OFF_D0IH;
  const float* WT_d0hh = ws + OFF_D0HH;
  const float* WT_d1ih = ws + OFF_D1IH;
  const float* WT_d1hh = ws + OFF_D1HH;
  const float* B_e0 = ws + OFF_BE0;
  const float* B_e1 = ws + OFF_BE1;
  const float* B_d0 = ws + OFF_BD0;
  const float* B_d1 = ws + OFF_BD1;

  // ---------------- encoder ----------------
  for (int t=0; t<TENC; ++t) {
    if (tid < 7*TB) {
      int s = tid / 7, d = tid - s*7;
      xs[d*XSTR + s] = target[(sbase + s)*(TENC*7) + t*7 + d];
    }
    __syncthreads();
    layer_step<7>(WT_e0ih, WT_e0hh, B_e0, xs,  h0s, c0, hh, my_s);
    layer_step<H>(WT_e1ih, WT_e1hh, B_e1, h0s, h1s, c1, hh, my_s);
  }

  // ---------------- decoder ----------------
  if (tid < 2*TB) {
    int o = tid >> 4, s = tid & 15;
    xs[o*XSTR + s] = 0.f;          // x0 = zeros(B,2)
  }
  __syncthreads();
  const float ob0 = outB[0], ob1 = outB[1];

  for (int p=0; p<TDEC; ++p) {
    layer_step<2>(WT_d0ih, WT_d0hh, B_d0, xs,  h0s, c0, hh, my_s);
    layer_step<H>(WT_d1ih, WT_d1hh, B_d1, h0s, h1s, c1, hh, my_s);

    // projection: pred[s][o] = h1[:,s] . outW[o,:] + outB[o]
    if (tid < 8*TB) {
      int s = tid & 15, oh = tid >> 4;       // oh = quarter*2 + o
      int o = oh & 1, quarter = oh >> 1;
      const float* wo = outW + o*128 + quarter*32;
      const float* hc = h1s + (quarter*32)*XSTR + s;
      float acc = 0.f;
      #pragma unroll 8
      for (int k=0; k<32; ++k) acc = fmaf(hc[k*XSTR], wo[k], acc);
      ps[oh*TB + s] = acc;
    }
    __syncthreads();
    if (tid < 2*TB) {
      int o = tid >> 4, s = tid & 15;
      float pred = ps[(0*2+o)*TB + s] + ps[(1*2+o)*TB + s]
                 + ps[(2*2+o)*TB + s] + ps[(3*2+o)*TB + s]
                 + (o ? ob1 : ob0);
      out[((sbase + s)*TDEC + p)*2 + o] = pred;
      xs[o*XSTR + s] = pred;               // x for next decoder step
    }
    __syncthreads();
  }
}

extern "C" void kernel_launch(void* const* d_in, const int* in_sizes, int n_in,
                              void* d_out, int out_size, void* d_ws, size_t ws_size,
                              hipStream_t stream)
{
  const float* target = (const float*)d_in[0];
  const float* e0ih=(const float*)d_in[4],  *e0hh=(const float*)d_in[5];
  const float* be0i=(const float*)d_in[6],  *be0h=(const float*)d_in[7];
  const float* e1ih=(const float*)d_in[8],  *e1hh=(const float*)d_in[9];
  const float* be1i=(const float*)d_in[10], *be1h=(const float*)d_in[11];
  const float* d0ih=(const float*)d_in[12], *d0hh=(const float*)d_in[13];
  const float* bd0i=(const float*)d_in[14], *bd0h=(const float*)d_in[15];
  const float* d1ih=(const float*)d_in[16], *d1hh=(const float*)d_in[17];
  const float* bd1i=(const float*)d_in[18], *bd1h=(const float*)d_in[19];
  const float* outW=(const float*)d_in[20], *outB=(const float*)d_in[21];
  float* ws  = (float*)d_ws;
  float* out = (float*)d_out;
  const int B = in_sizes[0] / (TENC*7);     // 65536

  hipLaunchKernelGGL(prep_kernel, dim3((WS_FLOATS+255)/256), dim3(256), 0, stream,
      e0ih,e0hh,e1ih,e1hh,d0ih,d0hh,d1ih,d1hh,
      be0i,be0h,be1i,be1h,bd0i,bd0h,bd1i,bd1h, ws);
  hipLaunchKernelGGL(lstm_main, dim3(B/TB), dim3(512), 0, stream,
      target, ws, outW, outB, out);
}

// Round 7
// 9829.373 us; speedup vs baseline: 2.1531x; 1.9377x over previous
//
#include <hip/hip_runtime.h>
#include <math.h>

typedef unsigned short u16;
typedef __attribute__((ext_vector_type(8))) short bf16x8;   // 8 bf16 in 4 VGPRs
typedef __attribute__((ext_vector_type(4))) float f32x4;

#define TENC 20
#define TDEC 25
#define MTB 32          // samples per block
#define HSTR 136        // h LDS row stride (u16): 272B, b128-aligned, 2-way banks
#define XSTRD 40        // x LDS row stride (u16): 80B, b128-aligned, 2-way banks

// ---- weight fragment layout in ws (u16 offsets) ----
// Per matrix: [pass(2: hi,lo)][kt][t(4)][w(8)][lane(64)][j(8)]  (16384 u16 per kt per pass)
// Element (pass,kt,t,w,l,j) = split_pass( W_orig[n][k] ), n = t*128 + w*16 + (l&15),
// k = kt*32 + (l>>4)*8 + j  (zero-padded if k >= K).
#define W_E0IH 0        // K=7  nkt=1
#define W_E0HH 32768    // K=128 nkt=4
#define W_E1IH 163840   // K=128 nkt=4
#define W_E1HH 294912   // K=128 nkt=4
#define W_D0IH 425984   // K=2  nkt=1
#define W_D0HH 458752   // K=128 nkt=4
#define W_D1IH 589824   // K=128 nkt=4
#define W_D1HH 720896   // K=128 nkt=4
#define W_TOTAL 851968
#define BIAS_BYTE_OFF (W_TOTAL*2)   // then 4 x 512 floats: e0,e1,d0,d1 fragments

__device__ __forceinline__ void split16(float v, u16& hi, u16& lo) {
  unsigned int u = __float_as_uint(v);
  hi = (u16)(u >> 16);                              // truncated bf16 hi
  float hif = __uint_as_float(u & 0xffff0000u);
  lo = (u16)(__float_as_uint(v - hif) >> 16);       // bf16(lo), residual ~2^-16 rel
}

__global__ void prep_kernel(
    const float* __restrict__ e0ih, const float* __restrict__ e0hh,
    const float* __restrict__ e1ih, const float* __restrict__ e1hh,
    const float* __restrict__ d0ih, const float* __restrict__ d0hh,
    const float* __restrict__ d1ih, const float* __restrict__ d1hh,
    const float* __restrict__ be0i, const float* __restrict__ be0h,
    const float* __restrict__ be1i, const float* __restrict__ be1h,
    const float* __restrict__ bd0i, const float* __restrict__ bd0h,
    const float* __restrict__ bd1i, const float* __restrict__ bd1h,
    u16* __restrict__ wsw, float* __restrict__ wsb)
{
  int idx = blockIdx.x * blockDim.x + threadIdx.x;
  if (idx < W_TOTAL) {
    const float* src; int K, nkt, off;
    if (idx < W_E0HH)      { src=e0ih; K=7;   nkt=1; off=W_E0IH; }
    else if (idx < W_E1IH) { src=e0hh; K=128; nkt=4; off=W_E0HH; }
    else if (idx < W_E1HH) { src=e1ih; K=128; nkt=4; off=W_E1IH; }
    else if (idx < W_D0IH) { src=e1hh; K=128; nkt=4; off=W_E1HH; }
    else if (idx < W_D0HH) { src=d0ih; K=2;   nkt=1; off=W_D0IH; }
    else if (idx < W_D1IH) { src=d0hh; K=128; nkt=4; off=W_D0HH; }
    else if (idx < W_D1HH) { src=d1ih; K=128; nkt=4; off=W_D1IH; }
    else                   { src=d1hh; K=128; nkt=4; off=W_D1HH; }
    int n = idx - off;
    int pass_sz = nkt * 16384;
    int pass = n / pass_sz; n -= pass * pass_sz;
    int kt = n >> 14;
    int r  = n & 16383;
    int t = r >> 12;
    int w = (r >> 9) & 7;
    int l = (r >> 3) & 63;
    int j = r & 7;
    int k  = kt*32 + (l >> 4)*8 + j;
    int ng = t*128 + w*16 + (l & 15);
    float v = (k < K) ? src[ng*K + k] : 0.0f;
    u16 hi, lo; split16(v, hi, lo);
    wsw[idx] = (pass == 0) ? hi : lo;
  } else if (idx < W_TOTAL + 2048) {
    int b = idx - W_TOTAL;
    int set = b >> 9, r = b & 511;
    int t = r & 3, hl = (r >> 2) & 15, w = r >> 6;
    int n = t*128 + w*16 + hl;
    float v;
    if      (set == 0) v = be0i[n] + be0h[n];
    else if (set == 1) v = be1i[n] + be1h[n];
    else if (set == 2) v = bd0i[n] + bd0h[n];
    else               v = bd1i[n] + bd1h[n];
    wsb[b] = v;
  }
}

__device__ __forceinline__ float sigm(float x) { return 1.0f / (1.0f + __expf(-x)); }
__device__ __forceinline__ float tanh_f(float x) {
  float e = __expf(2.0f * x);          // inf/0 saturate gracefully to +/-1
  return 1.0f - 2.0f / (e + 1.0f);
}

// acc[m(2)][t(4)] 16x16 tiles; A from LDS hi/lo bf16 arrays (row = sample, k-contig);
// B fragments streamed from prepped global. 3-term split: AhBh + AhBl + AlBh.
template<int NKT>
__device__ __forceinline__ void gemm_frag(f32x4 acc[2][4],
    const u16* Ahi, const u16* Alo, const int astride,
    const u16* __restrict__ Wf, int w, int l)
{
  const int g = l >> 4, hl = l & 15;
  #pragma unroll
  for (int kt = 0; kt < NKT; ++kt) {
    const int kb = kt*32 + g*8;
    bf16x8 ah0 = *(const bf16x8*)(Ahi + hl*astride + kb);
    bf16x8 ah1 = *(const bf16x8*)(Ahi + (16 + hl)*astride + kb);
    bf16x8 al0 = *(const bf16x8*)(Alo + hl*astride + kb);
    bf16x8 al1 = *(const bf16x8*)(Alo + (16 + hl)*astride + kb);
    #pragma unroll
    for (int t = 0; t < 4; ++t) {
      const u16* wp = Wf + (((kt*4 + t)*8 + w)*64 + l)*8;
      bf16x8 bh = *(const bf16x8*)(wp);
      bf16x8 bl = *(const bf16x8*)(wp + NKT*16384);
      acc[0][t] = __builtin_amdgcn_mfma_f32_16x16x32_bf16(ah0, bh, acc[0][t], 0, 0, 0);
      acc[1][t] = __builtin_amdgcn_mfma_f32_16x16x32_bf16(ah1, bh, acc[1][t], 0, 0, 0);
      acc[0][t] = __builtin_amdgcn_mfma_f32_16x16x32_bf16(ah0, bl, acc[0][t], 0, 0, 0);
      acc[1][t] = __builtin_amdgcn_mfma_f32_16x16x32_bf16(ah1, bl, acc[1][t], 0, 0, 0);
      acc[0][t] = __builtin_amdgcn_mfma_f32_16x16x32_bf16(al0, bh, acc[0][t], 0, 0, 0);
      acc[1][t] = __builtin_amdgcn_mfma_f32_16x16x32_bf16(al1, bh, acc[1][t], 0, 0, 0);
    }
  }
}

// One LSTM layer step for the block's 32-sample tile.
// acc tile t = gate t (i,f,g,o) for hiddens w*16+(l&15); C/D rows = samples.
template<int NKT_IH>
__device__ __forceinline__ void layer_step(
    const u16* xhi, const u16* xlo, int xstride,
    u16* hhi, u16* hlo,
    const u16* __restrict__ Wih, const u16* __restrict__ Whh,
    const float* __restrict__ biasf,
    float cC[2][4], int w, int l)
{
  const int g = l >> 4, hl = l & 15;
  f32x4 acc[2][4];
  float4 bb = *(const float4*)(biasf + (w*16 + hl)*4);
  const float bv[4] = {bb.x, bb.y, bb.z, bb.w};
  #pragma unroll
  for (int m = 0; m < 2; ++m)
    #pragma unroll
    for (int t = 0; t < 4; ++t) {
      f32x4 a; a[0] = bv[t]; a[1] = bv[t]; a[2] = bv[t]; a[3] = bv[t];
      acc[m][t] = a;
    }
  gemm_frag<NKT_IH>(acc, xhi, xlo, xstride, Wih, w, l);
  gemm_frag<4>(acc, hhi, hlo, HSTR, Whh, w, l);

  __syncthreads();   // all gemm reads of h done before overwrite
  #pragma unroll
  for (int m = 0; m < 2; ++m)
    #pragma unroll
    for (int r = 0; r < 4; ++r) {
      float iv = sigm(acc[m][0][r]);
      float fv = sigm(acc[m][1][r]);
      float gv = tanh_f(acc[m][2][r]);
      float ov = sigm(acc[m][3][r]);
      float c  = fv * cC[m][r] + iv * gv;
      cC[m][r] = c;
      float h  = ov * tanh_f(c);
      u16 a_, b_; split16(h, a_, b_);
      int row = m*16 + g*4 + r;            // C/D: row = (l>>4)*4 + reg
      hhi[row*HSTR + w*16 + hl] = a_;
      hlo[row*HSTR + w*16 + hl] = b_;
    }
  __syncthreads();
}

__global__ __launch_bounds__(512) void lstm_main(
    const float* __restrict__ target,
    const u16* __restrict__ wsw, const float* __restrict__ wsb,
    const float* __restrict__ outW, const float* __restrict__ outB,
    float* __restrict__ out)
{
  __shared__ u16 h0hi[32*HSTR], h0lo[32*HSTR];
  __shared__ u16 h1hi[32*HSTR], h1lo[32*HSTR];
  __shared__ u16 xhi[32*XSTRD], xlo[32*XSTRD];
  __shared__ float ps[256];

  const int tid = threadIdx.x;
  const int w = tid >> 6, l = tid & 63;
  const long sbase = (long)blockIdx.x * MTB;

  float c0[2][4], c1[2][4];
  #pragma unroll
  for (int m = 0; m < 2; ++m)
    #pragma unroll
    for (int r = 0; r < 4; ++r) { c0[m][r] = 0.f; c1[m][r] = 0.f; }

  for (int i = tid; i < 32*HSTR; i += 512) { h0hi[i]=0; h0lo[i]=0; h1hi[i]=0; h1lo[i]=0; }
  for (int i = tid; i < 32*XSTRD; i += 512) { xhi[i]=0; xlo[i]=0; }
  __syncthreads();

  // ---------------- encoder ----------------
  for (int t = 0; t < TENC; ++t) {
    {
      int s = tid >> 3, d = tid & 7;
      if (tid < 256 && d < 7) {
        float v = target[(sbase + s)*(TENC*7) + t*7 + d];
        u16 a_, b_; split16(v, a_, b_);
        xhi[s*XSTRD + d] = a_;
        xlo[s*XSTRD + d] = b_;
      }
    }
    __syncthreads();
    layer_step<1>(xhi, xlo, XSTRD, h0hi, h0lo, wsw + W_E0IH, wsw + W_E0HH, wsb + 0,    c0, w, l);
    layer_step<4>(h0hi, h0lo, HSTR, h1hi, h1lo, wsw + W_E1IH, wsw + W_E1HH, wsb + 512, c1, w, l);
  }

  // ---------------- decoder ----------------
  for (int i = tid; i < 32*XSTRD; i += 512) { xhi[i]=0; xlo[i]=0; }  // x0 = zeros(B,2)
  __syncthreads();
  const float ob0 = outB[0], ob1 = outB[1];

  for (int p = 0; p < TDEC; ++p) {
    layer_step<1>(xhi, xlo, XSTRD, h0hi, h0lo, wsw + W_D0IH, wsw + W_D0HH, wsb + 1024, c0, w, l);
    layer_step<4>(h0hi, h0lo, HSTR, h1hi, h1lo, wsw + W_D1IH, wsw + W_D1HH, wsb + 1536, c1, w, l);

    // projection: pred[s][o] = h1[s,:] . outW[o,:] + outB[o]
    if (tid < 256) {
      int s = tid & 31, oq = tid >> 5;     // oq = q*2 + o
      int o = oq & 1, q = oq >> 1;
      const float* wo = outW + o*128 + q*32;
      const u16* phh = h1hi + s*HSTR + q*32;
      const u16* phl = h1lo + s*HSTR + q*32;
      float a = 0.f;
      #pragma unroll 8
      for (int k = 0; k < 32; ++k) {
        float hv = __uint_as_float(((unsigned int)phh[k]) << 16)
                 + __uint_as_float(((unsigned int)phl[k]) << 16);
        a = fmaf(hv, wo[k], a);
      }
      ps[oq*32 + s] = a;
    }
    __syncthreads();
    if (tid < 64) {
      int s = tid & 31, o = tid >> 5;
      float pred = ps[(0+o)*32+s] + ps[(2+o)*32+s] + ps[(4+o)*32+s] + ps[(6+o)*32+s]
                 + (o ? ob1 : ob0);
      out[((sbase + s)*TDEC + p)*2 + o] = pred;
      u16 a_, b_; split16(pred, a_, b_);
      xhi[s*XSTRD + o] = a_;
      xlo[s*XSTRD + o] = b_;
    }
    __syncthreads();
  }
}

extern "C" void kernel_launch(void* const* d_in, const int* in_sizes, int n_in,
                              void* d_out, int out_size, void* d_ws, size_t ws_size,
                              hipStream_t stream)
{
  const float* target = (const float*)d_in[0];
  const float* e0ih=(const float*)d_in[4],  *e0hh=(const float*)d_in[5];
  const float* be0i=(const float*)d_in[6],  *be0h=(const float*)d_in[7];
  const float* e1ih=(const float*)d_in[8],  *e1hh=(const float*)d_in[9];
  const float* be1i=(const float*)d_in[10], *be1h=(const float*)d_in[11];
  const float* d0ih=(const float*)d_in[12], *d0hh=(const float*)d_in[13];
  const float* bd0i=(const float*)d_in[14], *bd0h=(const float*)d_in[15];
  const float* d1ih=(const float*)d_in[16], *d1hh=(const float*)d_in[17];
  const float* bd1i=(const float*)d_in[18], *bd1h=(const float*)d_in[19];
  const float* outW=(const float*)d_in[20], *outB=(const float*)d_in[21];
  u16*   wsw = (u16*)d_ws;
  float* wsb = (float*)((char*)d_ws + BIAS_BYTE_OFF);
  float* out = (float*)d_out;
  const int B = in_sizes[0] / (TENC*7);     // 65536

  hipLaunchKernelGGL(prep_kernel, dim3((W_TOTAL + 2048 + 255)/256), dim3(256), 0, stream,
      e0ih,e0hh,e1ih,e1hh,d0ih,d0hh,d1ih,d1hh,
      be0i,be0h,be1i,be1h,bd0i,bd0h,bd1i,bd1h, wsw, wsb);
  hipLaunchKernelGGL(lstm_main, dim3(B/MTB), dim3(512), 0, stream,
      target, wsw, wsb, outW, outB, out);
}

// Round 8
// 8290.713 us; speedup vs baseline: 2.5526x; 1.1856x over previous
//
#include <hip/hip_runtime.h>
#include <math.h>

typedef unsigned short u16;
typedef __attribute__((ext_vector_type(8))) short bf16x8;   // 8 bf16 in 4 VGPRs
typedef __attribute__((ext_vector_type(4))) float f32x4;

#define TENC 20
#define TDEC 25
#define MTB 64          // samples per block
#define HSTR 136        // h LDS row stride (u16): 272B, b128-aligned
#define XSTRD 40        // x LDS row stride (u16): 80B, b128-aligned

// ---- weight fragment layout in ws (u16 offsets) ----
// Per matrix: [kt][t(4)][w(8)][lane(64)][16: hi8|lo8]   (32768 u16 per kt)
// Element (kt,t,w,l,hi/lo j) = split( W_orig[n][k] ), n = t*128 + w*16 + (l&15),
// k = kt*32 + (l>>4)*8 + j  (zero-padded if k >= K).
// Matrix bases padded +512 u16 to break power-of-2 L2 set aliasing.
#define W_E0IH 0        // K=7   nkt=1  sz 32768
#define W_E0HH 33280    // K=128 nkt=4  sz 131072
#define W_E1IH 164864   // K=128 nkt=4
#define W_E1HH 296448   // K=128 nkt=4
#define W_D0IH 428032   // K=2   nkt=1  sz 32768
#define W_D0HH 461312   // K=128 nkt=4
#define W_D1IH 592896   // K=128 nkt=4
#define W_D1HH 724480   // K=128 nkt=4
#define W_TOTAL 855552
#define BIAS_BYTE_OFF (W_TOTAL*2)   // then 4 x 512 floats: e0,e1,d0,d1 fragments

__device__ __forceinline__ void split16(float v, u16& hi, u16& lo) {
  unsigned int u = __float_as_uint(v);
  hi = (u16)(u >> 16);                              // truncated bf16 hi
  float hif = __uint_as_float(u & 0xffff0000u);
  lo = (u16)(__float_as_uint(v - hif) >> 16);       // bf16(lo), residual ~2^-16 rel
}

__global__ void prep_kernel(
    const float* __restrict__ e0ih, const float* __restrict__ e0hh,
    const float* __restrict__ e1ih, const float* __restrict__ e1hh,
    const float* __restrict__ d0ih, const float* __restrict__ d0hh,
    const float* __restrict__ d1ih, const float* __restrict__ d1hh,
    const float* __restrict__ be0i, const float* __restrict__ be0h,
    const float* __restrict__ be1i, const float* __restrict__ be1h,
    const float* __restrict__ bd0i, const float* __restrict__ bd0h,
    const float* __restrict__ bd1i, const float* __restrict__ bd1h,
    u16* __restrict__ wsw, float* __restrict__ wsb)
{
  int idx = blockIdx.x * blockDim.x + threadIdx.x;
  if (idx < W_TOTAL) {
    const float* src; int K, nkt, off;
    if (idx < W_E0HH)      { src=e0ih; K=7;   nkt=1; off=W_E0IH; }
    else if (idx < W_E1IH) { src=e0hh; K=128; nkt=4; off=W_E0HH; }
    else if (idx < W_E1HH) { src=e1ih; K=128; nkt=4; off=W_E1IH; }
    else if (idx < W_D0IH) { src=e1hh; K=128; nkt=4; off=W_E1HH; }
    else if (idx < W_D0HH) { src=d0ih; K=2;   nkt=1; off=W_D0IH; }
    else if (idx < W_D1IH) { src=d0hh; K=128; nkt=4; off=W_D0HH; }
    else if (idx < W_D1HH) { src=d1ih; K=128; nkt=4; off=W_D1IH; }
    else                   { src=d1hh; K=128; nkt=4; off=W_D1HH; }
    int n = idx - off;
    if (n >= nkt*32768) { wsw[idx] = 0; return; }   // base-pad region
    int kt = n >> 15;
    int r  = n & 32767;
    int t   = r >> 13;
    int w   = (r >> 10) & 7;
    int l   = (r >> 4) & 63;
    int j16 = r & 15;
    int pass = j16 >> 3, j = j16 & 7;
    int k  = kt*32 + (l >> 4)*8 + j;
    int ng = t*128 + w*16 + (l & 15);
    float v = (k < K) ? src[ng*K + k] : 0.0f;
    u16 hi, lo; split16(v, hi, lo);
    wsw[idx] = (pass == 0) ? hi : lo;
  } else if (idx < W_TOTAL + 2048) {
    int b = idx - W_TOTAL;
    int set = b >> 9, r = b & 511;
    int t = r & 3, hl = (r >> 2) & 15, w = r >> 6;
    int n = t*128 + w*16 + hl;
    float v;
    if      (set == 0) v = be0i[n] + be0h[n];
    else if (set == 1) v = be1i[n] + be1h[n];
    else if (set == 2) v = bd0i[n] + bd0h[n];
    else               v = bd1i[n] + bd1h[n];
    wsb[b] = v;
  }
}

__device__ __forceinline__ float sigm(float x) { return 1.0f / (1.0f + __expf(-x)); }
__device__ __forceinline__ float tanh_f(float x) {
  float e = __expf(2.0f * x);          // inf/0 saturate gracefully to +/-1
  return 1.0f - 2.0f / (e + 1.0f);
}

// acc[m(4)][t(4)] 16x16 tiles; A from LDS hi/lo bf16 arrays (row = sample, k-contig);
// B fragments streamed from prepped global (hi/lo interleaved 32B).
// 3-term split: AhBh + AhBl + AlBh.
template<int NKT>
__device__ __forceinline__ void gemm_frag(f32x4 acc[4][4],
    const u16* Ahi, const u16* Alo, const int astride,
    const u16* __restrict__ Wf, int w, int l)
{
  const int g = l >> 4, hl = l & 15;
  #pragma unroll
  for (int kt = 0; kt < NKT; ++kt) {
    const int kb = kt*32 + g*8;
    bf16x8 ah[4], al[4];
    #pragma unroll
    for (int m = 0; m < 4; ++m) {
      ah[m] = *(const bf16x8*)(Ahi + (m*16 + hl)*astride + kb);
      al[m] = *(const bf16x8*)(Alo + (m*16 + hl)*astride + kb);
    }
    #pragma unroll
    for (int t = 0; t < 4; ++t) {
      const u16* wp = Wf + (((kt*4 + t)*8 + w)*64 + l)*16;
      bf16x8 bh = *(const bf16x8*)(wp);
      bf16x8 bl = *(const bf16x8*)(wp + 8);
      #pragma unroll
      for (int m = 0; m < 4; ++m) {
        acc[m][t] = __builtin_amdgcn_mfma_f32_16x16x32_bf16(ah[m], bh, acc[m][t], 0, 0, 0);
        acc[m][t] = __builtin_amdgcn_mfma_f32_16x16x32_bf16(ah[m], bl, acc[m][t], 0, 0, 0);
        acc[m][t] = __builtin_amdgcn_mfma_f32_16x16x32_bf16(al[m], bh, acc[m][t], 0, 0, 0);
      }
    }
  }
}

// One LSTM layer step for the block's 64-sample tile.
// acc tile t = gate t (i,f,g,o) for hiddens w*16+(l&15); C/D rows = samples.
template<int NKT_IH>
__device__ __forceinline__ void layer_step(
    const u16* xhi, const u16* xlo, int xstride,
    u16* hhi, u16* hlo,
    const u16* __restrict__ Wih, const u16* __restrict__ Whh,
    const float* __restrict__ biasf,
    float cC[4][4], int w, int l)
{
  const int g = l >> 4, hl = l & 15;
  f32x4 acc[4][4];
  float4 bb = *(const float4*)(biasf + (w*16 + hl)*4);
  const float bv[4] = {bb.x, bb.y, bb.z, bb.w};
  #pragma unroll
  for (int m = 0; m < 4; ++m)
    #pragma unroll
    for (int t = 0; t < 4; ++t) {
      f32x4 a; a[0] = bv[t]; a[1] = bv[t]; a[2] = bv[t]; a[3] = bv[t];
      acc[m][t] = a;
    }
  gemm_frag<NKT_IH>(acc, xhi, xlo, xstride, Wih, w, l);
  gemm_frag<4>(acc, hhi, hlo, HSTR, Whh, w, l);

  __syncthreads();   // all gemm reads of h done before overwrite
  #pragma unroll
  for (int m = 0; m < 4; ++m)
    #pragma unroll
    for (int r = 0; r < 4; ++r) {
      float iv = sigm(acc[m][0][r]);
      float fv = sigm(acc[m][1][r]);
      float gv = tanh_f(acc[m][2][r]);
      float ov = sigm(acc[m][3][r]);
      float c  = fv * cC[m][r] + iv * gv;
      cC[m][r] = c;
      float h  = ov * tanh_f(c);
      u16 a_, b_; split16(h, a_, b_);
      int row = m*16 + g*4 + r;            // C/D: row = (l>>4)*4 + reg
      hhi[row*HSTR + w*16 + hl] = a_;
      hlo[row*HSTR + w*16 + hl] = b_;
    }
  __syncthreads();
}

__global__ __launch_bounds__(512) void lstm_main(
    const float* __restrict__ target,
    const u16* __restrict__ wsw, const float* __restrict__ wsb,
    const float* __restrict__ outW, const float* __restrict__ outB,
    float* __restrict__ out)
{
  __shared__ u16 h0hi[MTB*HSTR], h0lo[MTB*HSTR];
  __shared__ u16 h1hi[MTB*HSTR], h1lo[MTB*HSTR];
  __shared__ u16 xhi[MTB*XSTRD], xlo[MTB*XSTRD];
  __shared__ float ps[8*MTB];

  const int tid = threadIdx.x;
  const int w = tid >> 6, l = tid & 63;
  const long sbase = (long)blockIdx.x * MTB;

  float c0[4][4], c1[4][4];
  #pragma unroll
  for (int m = 0; m < 4; ++m)
    #pragma unroll
    for (int r = 0; r < 4; ++r) { c0[m][r] = 0.f; c1[m][r] = 0.f; }

  for (int i = tid; i < MTB*HSTR; i += 512) { h0hi[i]=0; h0lo[i]=0; h1hi[i]=0; h1lo[i]=0; }
  for (int i = tid; i < MTB*XSTRD; i += 512) { xhi[i]=0; xlo[i]=0; }
  __syncthreads();

  // ---------------- encoder ----------------
  for (int t = 0; t < TENC; ++t) {
    if (tid < 7*MTB) {
      int s = tid / 7, d = tid - s*7;
      float v = target[(sbase + s)*(TENC*7) + t*7 + d];
      u16 a_, b_; split16(v, a_, b_);
      xhi[s*XSTRD + d] = a_;
      xlo[s*XSTRD + d] = b_;
    }
    __syncthreads();
    layer_step<1>(xhi, xlo, XSTRD, h0hi, h0lo, wsw + W_E0IH, wsw + W_E0HH, wsb + 0,    c0, w, l);
    layer_step<4>(h0hi, h0lo, HSTR, h1hi, h1lo, wsw + W_E1IH, wsw + W_E1HH, wsb + 512, c1, w, l);
  }

  // ---------------- decoder ----------------
  for (int i = tid; i < MTB*XSTRD; i += 512) { xhi[i]=0; xlo[i]=0; }  // x0 = zeros(B,2)
  __syncthreads();
  const float ob0 = outB[0], ob1 = outB[1];

  for (int p = 0; p < TDEC; ++p) {
    layer_step<1>(xhi, xlo, XSTRD, h0hi, h0lo, wsw + W_D0IH, wsw + W_D0HH, wsb + 1024, c0, w, l);
    layer_step<4>(h0hi, h0lo, HSTR, h1hi, h1lo, wsw + W_D1IH, wsw + W_D1HH, wsb + 1536, c1, w, l);

    // projection: pred[s][o] = h1[s,:] . outW[o,:] + outB[o]
    {
      int s = tid & (MTB-1), oq = tid >> 6;     // oq = q*2 + o
      int o = oq & 1, q = oq >> 1;
      const float* wo = outW + o*128 + q*32;
      const u16* phh = h1hi + s*HSTR + q*32;
      const u16* phl = h1lo + s*HSTR + q*32;
      float a = 0.f;
      #pragma unroll 8
      for (int k = 0; k < 32; ++k) {
        float hv = __uint_as_float(((unsigned int)phh[k]) << 16)
                 + __uint_as_float(((unsigned int)phl[k]) << 16);
        a = fmaf(hv, wo[k], a);
      }
      ps[oq*MTB + s] = a;
    }
    __syncthreads();
    if (tid < 2*MTB) {
      int s = tid & (MTB-1), o = tid >> 6;
      float pred = ps[(0+o)*MTB+s] + ps[(2+o)*MTB+s] + ps[(4+o)*MTB+s] + ps[(6+o)*MTB+s]
                 + (o ? ob1 : ob0);
      out[((sbase + s)*TDEC + p)*2 + o] = pred;
      u16 a_, b_; split16(pred, a_, b_);
      xhi[s*XSTRD + o] = a_;
      xlo[s*XSTRD + o] = b_;
    }
    __syncthreads();
  }
}

extern "C" void kernel_launch(void* const* d_in, const int* in_sizes, int n_in,
                              void* d_out, int out_size, void* d_ws, size_t ws_size,
                              hipStream_t stream)
{
  const float* target = (const float*)d_in[0];
  const float* e0ih=(const float*)d_in[4],  *e0hh=(const float*)d_in[5];
  const float* be0i=(const float*)d_in[6],  *be0h=(const float*)d_in[7];
  const float* e1ih=(const float*)d_in[8],  *e1hh=(const float*)d_in[9];
  const float* be1i=(const float*)d_in[10], *be1h=(const float*)d_in[11];
  const float* d0ih=(const float*)d_in[12], *d0hh=(const float*)d_in[13];
  const float* bd0i=(const float*)d_in[14], *bd0h=(const float*)d_in[15];
  const float* d1ih=(const float*)d_in[16], *d1hh=(const float*)d_in[17];
  const float* bd1i=(const float*)d_in[18], *bd1h=(const float*)d_in[19];
  const float* outW=(const float*)d_in[20], *outB=(const float*)d_in[21];
  u16*   wsw = (u16*)d_ws;
  float* wsb = (float*)((char*)d_ws + BIAS_BYTE_OFF);
  float* out = (float*)d_out;
  const int B = in_sizes[0] / (TENC*7);     // 65536

  hipLaunchKernelGGL(prep_kernel, dim3((W_TOTAL + 2048 + 255)/256), dim3(256), 0, stream,
      e0ih,e0hh,e1ih,e1hh,d0ih,d0hh,d1ih,d1hh,
      be0i,be0h,be1i,be1h,bd0i,bd0h,bd1i,bd1h, wsw, wsb);
  hipLaunchKernelGGL(lstm_main, dim3(B/MTB), dim3(512), 0, stream,
      target, wsw, wsb, outW, outB, out);
}